// Round 2
// baseline (2629.352 us; speedup 1.0000x reference)
//
#include <hip/hip_runtime.h>
#include <hip/hip_bf16.h>
#include <math.h>

// GatingFunc: logits = x @ W^T + b; top-2 -> softmax -> scatter to [N, E].
// N=131072, D=1024, E=64, K=2 (fp32 in, fp32 out).
//
// Round 2: fix round-1's two pathologies (seen via VGPR_Count=40 + 148MB WRITE_SIZE):
//  1. acc[64] was demoted to scratch -> keep accumulators as 4x ext_vector_type(16)
//     SSA values (no alloca exists, promotion is guaranteed).
//  2. wave-uniform W loads became s_load (64 quads = 256 SGPRs > 102 budget ->
//     serialized lgkmcnt(0) waits). Blind the uniformity analysis with an opaque
//     VGPR zero so W goes through global_load_dwordx4 + pipelined vmcnt waits.
//     Per-dc W working set = 64 lines (4KB) -> L1-resident, 75% line reuse.

#define D_MODEL 1024
#define N_EXP   64

typedef float v16f __attribute__((ext_vector_type(16)));

__global__ __launch_bounds__(256) void gating_kernel(
    const float* __restrict__ x,
    const float* __restrict__ W,
    const float* __restrict__ b,
    float* __restrict__ out,
    int n_tokens)
{
    const int t = blockIdx.x * blockDim.x + threadIdx.x;
    if (t >= n_tokens) return;

    // Opaque zero living in a VGPR: makes W addresses formally divergent so the
    // compiler emits pipelined global_load_dwordx4 instead of s_load.
    int vzero = 0;
    asm volatile("" : "+v"(vzero));

    const float4* __restrict__ x4 =
        reinterpret_cast<const float4*>(x) + (size_t)t * (D_MODEL / 4);
    const float4* __restrict__ W4 =
        reinterpret_cast<const float4*>(W) + vzero;

    v16f acc0, acc1, acc2, acc3;
#pragma unroll
    for (int j = 0; j < 16; ++j) {
        acc0[j] = b[j];
        acc1[j] = b[16 + j];
        acc2[j] = b[32 + j];
        acc3[j] = b[48 + j];
    }

    // Main GEMV, x prefetched one iteration ahead; W pipelined by vmcnt.
    float4 xv = x4[0];
    for (int dc = 0; dc < D_MODEL / 4; ++dc) {
        const float4 xn = x4[(dc + 1) & (D_MODEL / 4 - 1)];
#define GROUP(ACC, G)                                                   \
        _Pragma("unroll")                                               \
        for (int j = 0; j < 16; ++j) {                                  \
            const float4 wv = W4[((G) * 16 + j) * (D_MODEL / 4) + dc];  \
            float a = ACC[j];                                           \
            a = fmaf(xv.x, wv.x, a);                                    \
            a = fmaf(xv.y, wv.y, a);                                    \
            a = fmaf(xv.z, wv.z, a);                                    \
            a = fmaf(xv.w, wv.w, a);                                    \
            ACC[j] = a;                                                 \
        }
        GROUP(acc0, 0)
        GROUP(acc1, 1)
        GROUP(acc2, 2)
        GROUP(acc3, 3)
#undef GROUP
        xv = xn;
    }

    // Top-2 (ascending e, strict '>' keeps lower index on ties, matching
    // jax.lax.top_k).
    float m1 = -INFINITY, m2 = -INFINITY;
    int i1 = 0, i2 = 0;
#define SCAN(ACC, G)                                                    \
    _Pragma("unroll")                                                   \
    for (int j = 0; j < 16; ++j) {                                      \
        const float v = ACC[j];                                         \
        const int e = (G) * 16 + j;                                     \
        if (v > m1) { m2 = m1; i2 = i1; m1 = v; i1 = e; }               \
        else if (v > m2) { m2 = v; i2 = e; }                            \
    }
    SCAN(acc0, 0)
    SCAN(acc1, 1)
    SCAN(acc2, 2)
    SCAN(acc3, 3)
#undef SCAN

    // Softmax over the two selected logits (m1 >= m2).
    const float e2 = expf(m2 - m1);
    const float inv = 1.0f / (1.0f + e2);
    const float g1 = inv;
    const float g2 = e2 * inv;

    // Scatter row: zeros except columns i1, i2.
    float4* __restrict__ out4 = reinterpret_cast<float4*>(out + (size_t)t * N_EXP);
#pragma unroll
    for (int c = 0; c < N_EXP / 4; ++c) {
        float4 o;
        const int e0 = c * 4;
        o.x = (e0 + 0 == i1) ? g1 : ((e0 + 0 == i2) ? g2 : 0.0f);
        o.y = (e0 + 1 == i1) ? g1 : ((e0 + 1 == i2) ? g2 : 0.0f);
        o.z = (e0 + 2 == i1) ? g1 : ((e0 + 2 == i2) ? g2 : 0.0f);
        o.w = (e0 + 3 == i1) ? g1 : ((e0 + 3 == i2) ? g2 : 0.0f);
        out4[c] = o;
    }
}

extern "C" void kernel_launch(void* const* d_in, const int* in_sizes, int n_in,
                              void* d_out, int out_size, void* d_ws, size_t ws_size,
                              hipStream_t stream) {
    const float* x = (const float*)d_in[0];
    const float* W = (const float*)d_in[1];
    const float* b = (const float*)d_in[2];
    float* out = (float*)d_out;

    const int n_tokens = in_sizes[0] / D_MODEL;   // 131072
    const int block = 256;
    const int grid = (n_tokens + block - 1) / block;  // 512 blocks

    gating_kernel<<<grid, block, 0, stream>>>(x, W, b, out, n_tokens);
}

// Round 3
// 1099.476 us; speedup vs baseline: 2.3915x; 2.3915x over previous
//
#include <hip/hip_runtime.h>
#include <hip/hip_bf16.h>
#include <math.h>

// GatingFunc: logits = x @ W^T + b; top-2 -> softmax -> scatter to [N, E].
// N=131072, D=1024, E=64, K=2 (fp32 in/out).
//
// Round 3 structure:
//  - __launch_bounds__(256, 1): grid gives only 4 waves/CU (1/SIMD), so grant
//    the full 512-VGPR budget. Rounds 1-2 got VGPR_Count=40/48: the compiler
//    parked the 64 accumulators in AGPRs (v_accvgpr round-trips, 3x VALU) or
//    scratch. 128 fp32 accs must live in arch VGPRs.
//  - W staged in LDS (32KB chunk = 64 experts x 128 cols). Inner-loop W reads
//    are the SAME address across all 64 lanes -> LDS broadcast (conflict-free),
//    DS pipe overlaps VALU. No SGPR pressure (round 1), no VMEM latency (round 2).
//  - 2 tokens/thread: each W quad feeds 8 FMAs -> DS traffic 2x under VALU floor.
//  - x prefetch distance 2; next W chunk prefetched into regs during compute.
// VALU floor: 8.6e9 FMA -> 109 us. Target 130-180 us.

#define D_MODEL 1024
#define N_EXP   64
#define NQ      256        // float4 quads per x row
#define CHUNK_Q 32         // quads per W chunk (128 columns)
#define N_CHUNK 8
#define BLOCK   256

typedef float v16f __attribute__((ext_vector_type(16)));

__global__ __launch_bounds__(BLOCK, 1) void gating_kernel(
    const float* __restrict__ x,
    const float* __restrict__ W,
    const float* __restrict__ b,
    float* __restrict__ out,
    int n_tokens)
{
    __shared__ float4 Wl[N_EXP * CHUNK_Q];   // 32 KB: slot s = e*32 + q

    const int tid = threadIdx.x;
    const int t0 = blockIdx.x * (BLOCK * 2) + tid;
    const int t1 = t0 + BLOCK;
    const int tmax = n_tokens - 1;
    const int t0c = t0 <= tmax ? t0 : tmax;
    const int t1c = t1 <= tmax ? t1 : tmax;

    const float4* __restrict__ x0p = reinterpret_cast<const float4*>(x) + (size_t)t0c * NQ;
    const float4* __restrict__ x1p = reinterpret_cast<const float4*>(x) + (size_t)t1c * NQ;
    const float4* __restrict__ W4 = reinterpret_cast<const float4*>(W);

    // ---- accumulators: 8 x v16f = 128 fp32, initialized with bias ----
    v16f A00, A01, A02, A03, A10, A11, A12, A13;
#pragma unroll
    for (int j = 0; j < 16; ++j) {
        const float b0 = b[j], b1 = b[16 + j], b2 = b[32 + j], b3 = b[48 + j];
        A00[j] = b0; A01[j] = b1; A02[j] = b2; A03[j] = b3;
        A10[j] = b0; A11[j] = b1; A12[j] = b2; A13[j] = b3;
    }

    // ---- stage W chunk 0 into LDS ----
#pragma unroll
    for (int i = 0; i < 8; ++i) {
        const int s = i * BLOCK + tid;           // 2048 slots
        const int e = s >> 5, qq = s & 31;
        Wl[s] = W4[(size_t)e * NQ + qq];
    }
    __syncthreads();

    // ---- x rolling prefetch (distance 2) ----
    float4 cur0 = x0p[0], cur1 = x1p[0];
    float4 nx0  = x0p[1], nx1  = x1p[1];

    for (int c = 0; c < N_CHUNK; ++c) {
        // prefetch next W chunk into registers while computing this one
        float4 wnx[8];
        if (c + 1 < N_CHUNK) {
#pragma unroll
            for (int i = 0; i < 8; ++i) {
                const int s = i * BLOCK + tid;
                const int e = s >> 5, qq = s & 31;
                wnx[i] = W4[(size_t)e * NQ + (c + 1) * CHUNK_Q + qq];
            }
        }

#pragma unroll 2
        for (int q = 0; q < CHUNK_Q; ++q) {
            const int g = c * CHUNK_Q + q;
            const float4 xa0 = cur0, xa1 = cur1;
            cur0 = nx0; cur1 = nx1;
            const int gp = (g + 2 <= NQ - 1) ? (g + 2) : (NQ - 1);
            nx0 = x0p[gp]; nx1 = x1p[gp];

#define EGRP(ACC0, ACC1, G)                                             \
            _Pragma("unroll")                                           \
            for (int j = 0; j < 16; ++j) {                              \
                const float4 wv = Wl[((G) * 16 + j) * CHUNK_Q + q];     \
                float s0 = ACC0[j];                                     \
                s0 = fmaf(xa0.x, wv.x, s0);                             \
                s0 = fmaf(xa0.y, wv.y, s0);                             \
                s0 = fmaf(xa0.z, wv.z, s0);                             \
                s0 = fmaf(xa0.w, wv.w, s0);                             \
                ACC0[j] = s0;                                           \
                float s1 = ACC1[j];                                     \
                s1 = fmaf(xa1.x, wv.x, s1);                             \
                s1 = fmaf(xa1.y, wv.y, s1);                             \
                s1 = fmaf(xa1.z, wv.z, s1);                             \
                s1 = fmaf(xa1.w, wv.w, s1);                             \
                ACC1[j] = s1;                                           \
            }
            EGRP(A00, A10, 0)
            EGRP(A01, A11, 1)
            EGRP(A02, A12, 2)
            EGRP(A03, A13, 3)
#undef EGRP
        }

        __syncthreads();   // all lanes done reading Wl
        if (c + 1 < N_CHUNK) {
#pragma unroll
            for (int i = 0; i < 8; ++i) Wl[i * BLOCK + tid] = wnx[i];
        }
        __syncthreads();   // chunk published
    }

    // ---- top-2, softmax, scatter (per token) ----
#define FINISH(AA0, AA1, AA2, AA3, TOK)                                 \
    {                                                                   \
        float m1 = -INFINITY, m2 = -INFINITY;                           \
        int i1 = 0, i2 = 0;                                             \
        _Pragma("unroll")                                               \
        for (int j = 0; j < 16; ++j) {                                  \
            const float v0_ = AA0[j];                                   \
            if (v0_ > m1) { m2 = m1; i2 = i1; m1 = v0_; i1 = j; }       \
            else if (v0_ > m2) { m2 = v0_; i2 = j; }                    \
            const float v1_ = AA1[j];                                   \
            if (v1_ > m1) { m2 = m1; i2 = i1; m1 = v1_; i1 = 16 + j; }  \
            else if (v1_ > m2) { m2 = v1_; i2 = 16 + j; }               \
            const float v2_ = AA2[j];                                   \
            if (v2_ > m1) { m2 = m1; i2 = i1; m1 = v2_; i1 = 32 + j; }  \
            else if (v2_ > m2) { m2 = v2_; i2 = 32 + j; }               \
            const float v3_ = AA3[j];                                   \
            if (v3_ > m1) { m2 = m1; i2 = i1; m1 = v3_; i1 = 48 + j; }  \
            else if (v3_ > m2) { m2 = v3_; i2 = 48 + j; }               \
        }                                                               \
        const float e2_ = expf(m2 - m1);                                \
        const float inv_ = 1.0f / (1.0f + e2_);                         \
        const float g1_ = inv_, g2_ = e2_ * inv_;                       \
        if ((TOK) < n_tokens) {                                         \
            float4* __restrict__ o4 =                                   \
                reinterpret_cast<float4*>(out + (size_t)(TOK) * N_EXP); \
            _Pragma("unroll")                                           \
            for (int cc = 0; cc < N_EXP / 4; ++cc) {                    \
                float4 o;                                               \
                const int e0 = cc * 4;                                  \
                o.x = (e0 + 0 == i1) ? g1_ : ((e0 + 0 == i2) ? g2_ : 0.0f); \
                o.y = (e0 + 1 == i1) ? g1_ : ((e0 + 1 == i2) ? g2_ : 0.0f); \
                o.z = (e0 + 2 == i1) ? g1_ : ((e0 + 2 == i2) ? g2_ : 0.0f); \
                o.w = (e0 + 3 == i1) ? g1_ : ((e0 + 3 == i2) ? g2_ : 0.0f); \
                o4[cc] = o;                                             \
            }                                                           \
        }                                                               \
    }
    FINISH(A00, A01, A02, A03, t0)
    FINISH(A10, A11, A12, A13, t1)
#undef FINISH
}

extern "C" void kernel_launch(void* const* d_in, const int* in_sizes, int n_in,
                              void* d_out, int out_size, void* d_ws, size_t ws_size,
                              hipStream_t stream) {
    const float* x = (const float*)d_in[0];
    const float* W = (const float*)d_in[1];
    const float* b = (const float*)d_in[2];
    float* out = (float*)d_out;

    const int n_tokens = in_sizes[0] / D_MODEL;             // 131072
    const int grid = (n_tokens + BLOCK * 2 - 1) / (BLOCK * 2);  // 256 blocks

    gating_kernel<<<grid, BLOCK, 0, stream>>>(x, W, b, out, n_tokens);
}